// Round 1
// baseline (723.406 us; speedup 1.0000x reference)
//
#include <hip/hip_runtime.h>
#include <math.h>

#define BB 2
#define CC 256
#define NHEAD 8
#define HD 32
#define NGRP 8
#define NN 32768
#define ATT_EPS 1e-6f
#define GN_EPS 1e-5f

#define KB_GN 64            // blocks per group for GN stats
#define TN3 128             // token tile, kernel 3
#define KC3 64              // K chunk, kernel 3
#define NT3 (NN / TN3)      // 256 token tiles
#define TN6 128             // token tile, kernel 6
#define MT6 64              // M tile, kernel 6

// ---- workspace layout (float offsets) ----
#define WS_QM      0ull
#define WS_PART3   (WS_QM + (size_t)BB*CC*NN)            // 16,777,216
#define WS_GNPART  (WS_PART3 + (size_t)BB*NHEAD*NT3*1056) // + 4,325,376
#define WS_SCALE   (WS_GNPART + 2048)
#define WS_SHIFT   (WS_SCALE + 512)
#define WS_CTX     (WS_SHIFT + 512)
#define WS_KSUM    (WS_CTX + 16384)
#define WS_AMAT    (WS_KSUM + 512)

// ============ Kernel 1: GroupNorm partial sums ============
__global__ __launch_bounds__(256) void gn_stats(const float* __restrict__ x,
                                                float* __restrict__ part) {
    int grp = blockIdx.x / KB_GN;   // 0..15  (b*8+g); group data is contiguous
    int blk = blockIdx.x % KB_GN;
    const float* base = x + (size_t)grp * (CC / NGRP) * NN + (size_t)blk * 16384;
    int t = threadIdx.x;
    float s = 0.f, s2 = 0.f;
    for (int i = 0; i < 16; ++i) {
        const float4 v = *(const float4*)(base + i * 1024 + t * 4);
        s  += v.x + v.y + v.z + v.w;
        s2 += v.x * v.x + v.y * v.y + v.z * v.z + v.w * v.w;
    }
    for (int off = 32; off; off >>= 1) {
        s  += __shfl_down(s, off);
        s2 += __shfl_down(s2, off);
    }
    __shared__ float ls[4], ls2[4];
    int wave = t >> 6;
    if ((t & 63) == 0) { ls[wave] = s; ls2[wave] = s2; }
    __syncthreads();
    if (t == 0) {
        part[(grp * KB_GN + blk) * 2 + 0] = ls[0] + ls[1] + ls[2] + ls[3];
        part[(grp * KB_GN + blk) * 2 + 1] = ls2[0] + ls2[1] + ls2[2] + ls2[3];
    }
}

// ============ Kernel 2: finalize GN -> per (b,c) scale/shift ============
__global__ __launch_bounds__(256) void gn_finalize(const float* __restrict__ part,
                                                   const float* __restrict__ gamma,
                                                   const float* __restrict__ beta,
                                                   float* __restrict__ scale,
                                                   float* __restrict__ shift) {
    __shared__ float mean_s[16], rstd_s[16];
    int t = threadIdx.x;
    if (t < 16) {
        float s = 0.f, s2 = 0.f;
        for (int i = 0; i < KB_GN; ++i) {
            s  += part[(t * KB_GN + i) * 2 + 0];
            s2 += part[(t * KB_GN + i) * 2 + 1];
        }
        const float inv = 1.0f / (float)((CC / NGRP) * NN);
        float m = s * inv;
        float var = s2 * inv - m * m;
        mean_s[t] = m;
        rstd_s[t] = rsqrtf(var + GN_EPS);
    }
    __syncthreads();
    for (int idx = t; idx < BB * CC; idx += 256) {
        int b = idx / CC, c = idx % CC;
        int grp = b * NGRP + c / (CC / NGRP);
        float sc = gamma[c] * rstd_s[grp];
        scale[idx] = sc;
        shift[idx] = beta[c] - mean_s[grp] * sc;
    }
}

// ============ Kernel 3: fused QKV GEMM + elu + context/ksum partials ============
// block = (token tile, head, batch). Computes q,k,v rows [h*32, h*32+32) for 128
// tokens. qm -> global; km,v -> LDS only; accumulates 32x32 context partial.
__global__ __launch_bounds__(256) void qkv_ctx(
    const float* __restrict__ x, const float* __restrict__ scale,
    const float* __restrict__ shift,
    const float* __restrict__ wq, const float* __restrict__ wk,
    const float* __restrict__ wv,
    float* __restrict__ qm_g, float* __restrict__ part) {
    int tile = blockIdx.x, h = blockIdx.y, b = blockIdx.z;
    int n0 = tile * TN3;
    int t = threadIdx.x;
    __shared__ float xs[KC3][TN3 + 4];        // 64 x 132
    __shared__ float wsh[3][KC3][HD + 1];     // transposed weight chunks [k][m]
    float aq[4][4] = {}, ak[4][4] = {}, av[4][4] = {};
    int r0 = (t >> 5) << 2;   // output row group (0..28)
    int c0 = (t & 31) << 2;   // token col group (0..124)
    const float* W[3] = {wq, wk, wv};

    for (int cc = 0; cc < CC; cc += KC3) {
        // stage xn tile (normalize on the fly)
        for (int i = 0; i < 8; ++i) {
            int row = i * 8 + (t >> 5);
            int ch = cc + row;
            float sc = scale[b * CC + ch], sh = shift[b * CC + ch];
            const float4 v = *(const float4*)(x + (size_t)(b * CC + ch) * NN + n0 + c0);
            float4 o;
            o.x = v.x * sc + sh; o.y = v.y * sc + sh;
            o.z = v.z * sc + sh; o.w = v.w * sc + sh;
            *(float4*)&xs[row][c0] = o;
        }
        // stage weight chunks transposed: wsh[mat][k][m]
        {
            int k = t & 63, mb = t >> 6;  // mb 0..3
            for (int mat = 0; mat < 3; ++mat) {
                const float* Wm = W[mat];
                for (int j = 0; j < 8; ++j) {
                    int m = j * 4 + mb;
                    wsh[mat][k][m] = Wm[(size_t)(h * HD + m) * CC + cc + k];
                }
            }
        }
        __syncthreads();
        for (int k = 0; k < KC3; ++k) {
            const float4 xv = *(const float4*)&xs[k][c0];
            const float xr[4] = {xv.x, xv.y, xv.z, xv.w};
            #pragma unroll
            for (int i = 0; i < 4; ++i) {
                float wqv = wsh[0][k][r0 + i];
                float wkv = wsh[1][k][r0 + i];
                float wvv = wsh[2][k][r0 + i];
                #pragma unroll
                for (int j = 0; j < 4; ++j) {
                    aq[i][j] += wqv * xr[j];
                    ak[i][j] += wkv * xr[j];
                    av[i][j] += wvv * xr[j];
                }
            }
        }
        __syncthreads();
    }

    // qm = elu(q)+1 -> global
    #pragma unroll
    for (int i = 0; i < 4; ++i) {
        int ch = h * HD + r0 + i;
        float4 o;
        o.x = aq[i][0] > 0.f ? aq[i][0] + 1.f : expf(aq[i][0]);
        o.y = aq[i][1] > 0.f ? aq[i][1] + 1.f : expf(aq[i][1]);
        o.z = aq[i][2] > 0.f ? aq[i][2] + 1.f : expf(aq[i][2]);
        o.w = aq[i][3] > 0.f ? aq[i][3] + 1.f : expf(aq[i][3]);
        *(float4*)(qm_g + (size_t)(b * CC + ch) * NN + n0 + c0) = o;
    }

    // km = elu(k)+1 and v -> LDS (overlay xs, which is free now)
    float* km_s = &xs[0][0];                 // rows 0..31, stride 132
    float* v_s  = &xs[32][0];                // rows 32..63
    #pragma unroll
    for (int i = 0; i < 4; ++i)
        #pragma unroll
        for (int j = 0; j < 4; ++j) {
            float kv = ak[i][j];
            km_s[(r0 + i) * (TN3 + 4) + c0 + j] = kv > 0.f ? kv + 1.f : expf(kv);
            v_s [(r0 + i) * (TN3 + 4) + c0 + j] = av[i][j];
        }
    __syncthreads();

    // context partial: ctx[d][e] += sum_n km[d][n]*v[e][n]
    int d = t >> 3;            // 0..31
    int e0 = (t & 7) << 2;     // 0..28
    float c4[4] = {0.f, 0.f, 0.f, 0.f};
    for (int n = 0; n < TN3; ++n) {
        float kmv = km_s[d * (TN3 + 4) + n];
        #pragma unroll
        for (int j = 0; j < 4; ++j) c4[j] += kmv * v_s[(e0 + j) * (TN3 + 4) + n];
    }
    size_t pb = (size_t)((b * NHEAD + h) * NT3 + tile) * 1056;
    #pragma unroll
    for (int j = 0; j < 4; ++j) part[pb + t * 4 + j] = c4[j];
    if (t < 32) {
        float s = 0.f;
        for (int n = 0; n < TN3; ++n) s += km_s[t * (TN3 + 4) + n];
        part[pb + 1024 + t] = s;
    }
}

// ============ Kernel 4: reduce context/ksum partials ============
__global__ __launch_bounds__(1024) void ctx_reduce(const float* __restrict__ part,
                                                   float* __restrict__ ctx,
                                                   float* __restrict__ ksum) {
    int bh = blockIdx.x;         // 0..15
    int t = threadIdx.x;         // 0..1023
    const float* p = part + (size_t)bh * NT3 * 1056;
    float acc = 0.f, ks = 0.f;
    for (int tile = 0; tile < NT3; ++tile) {
        acc += p[(size_t)tile * 1056 + t];
        if (t < 32) ks += p[(size_t)tile * 1056 + 1024 + t];
    }
    ctx[(size_t)bh * 1024 + t] = acc;
    if (t < 32) ksum[bh * 32 + t] = ks;
}

// ============ Kernel 5: A[b][o][h*32+d] = sum_e w_out[o][h*32+e]*ctx[b][h][d][e] ============
__global__ __launch_bounds__(256) void build_A(const float* __restrict__ w_out,
                                               const float* __restrict__ ctx,
                                               float* __restrict__ A) {
    int ot = blockIdx.x;   // 0..7 (32-row tile of o)
    int b = blockIdx.y;
    int t = threadIdx.x;   // destination column c = h*32+d
    __shared__ float cs[NHEAD][HD][HD];
    for (int i = t; i < NHEAD * HD * HD; i += 256)
        ((float*)cs)[i] = ctx[(size_t)b * NHEAD * HD * HD + i];
    __syncthreads();
    int h = t >> 5, d = t & 31;
    for (int oi = 0; oi < 32; ++oi) {
        int o = ot * 32 + oi;
        const float* wrow = w_out + (size_t)o * CC + h * HD;
        float s = 0.f;
        #pragma unroll
        for (int e = 0; e < HD; ++e) s += wrow[e] * cs[h][d][e];
        A[((size_t)b * CC + o) * CC + t] = s;
    }
}

// ============ Kernel 6: denom + scaled GEMM with A + bias + residual ============
__global__ __launch_bounds__(256) void final_out(
    const float* __restrict__ qm_g, const float* __restrict__ A,
    const float* __restrict__ ksum, const float* __restrict__ b_out,
    const float* __restrict__ x, float* __restrict__ out) {
    int tile = blockIdx.x, mt = blockIdx.y, b = blockIdx.z;
    int n0 = tile * TN6;
    int t = threadIdx.x;
    __shared__ float qs[HD][TN6 + 4];     // 32 x 132
    __shared__ float as[HD][MT6 + 4];     // A chunk transposed [k][m]
    __shared__ float den_s[TN6];
    __shared__ float ksum_s[HD];
    float acc[4][8] = {};
    int r0 = (t >> 4) << 2;    // 0..60
    int c0 = (t & 15) << 3;    // 0..120

    for (int h = 0; h < NHEAD; ++h) {
        // stage qm chunk (this head's 32 channels x 128 tokens)
        {
            int col = (t & 31) << 2;
            for (int i = 0; i < 4; ++i) {
                int row = i * 8 + (t >> 5);
                *(float4*)&qs[row][col] =
                    *(const float4*)(qm_g + (size_t)(b * CC + h * HD + row) * NN + n0 + col);
            }
        }
        // stage A chunk transposed
        {
            int k = t & 31, mb = t >> 5;   // mb 0..7
            for (int j = 0; j < 8; ++j) {
                int m = j * 8 + mb;
                as[k][m] = A[((size_t)(b * CC + mt * MT6 + m)) * CC + h * HD + k];
            }
        }
        if (t < HD) ksum_s[t] = ksum[(b * NHEAD + h) * HD + t];
        __syncthreads();
        // denominator per token for this head
        if (t < TN6) {
            float s = 0.f;
            #pragma unroll
            for (int d = 0; d < HD; ++d) s += qs[d][t] * ksum_s[d];
            den_s[t] = 1.0f / (s + ATT_EPS);
        }
        __syncthreads();
        // scale qm chunk in place by 1/denom
        {
            int col = t & 127;
            int rr0 = (t >> 7) << 4;  // 0 or 16
            float sden = den_s[col];
            for (int r = 0; r < 16; ++r) qs[rr0 + r][col] *= sden;
        }
        __syncthreads();
        // GEMM partial: acc += A_chunk^T-tile * qs
        for (int k = 0; k < HD; ++k) {
            float a4[4];
            #pragma unroll
            for (int i = 0; i < 4; ++i) a4[i] = as[k][r0 + i];
            const float4 qv0 = *(const float4*)&qs[k][c0];
            const float4 qv1 = *(const float4*)&qs[k][c0 + 4];
            const float qr[8] = {qv0.x, qv0.y, qv0.z, qv0.w, qv1.x, qv1.y, qv1.z, qv1.w};
            #pragma unroll
            for (int i = 0; i < 4; ++i)
                #pragma unroll
                for (int j = 0; j < 8; ++j) acc[i][j] += a4[i] * qr[j];
        }
        __syncthreads();
    }

    // epilogue: + b_out + residual x
    #pragma unroll
    for (int i = 0; i < 4; ++i) {
        int o = mt * MT6 + r0 + i;
        size_t base = ((size_t)(b * CC + o)) * NN + n0 + c0;
        float bo = b_out[o];
        float4 x0 = *(const float4*)(x + base);
        float4 x1 = *(const float4*)(x + base + 4);
        float4 o0, o1;
        o0.x = acc[i][0] + bo + x0.x; o0.y = acc[i][1] + bo + x0.y;
        o0.z = acc[i][2] + bo + x0.z; o0.w = acc[i][3] + bo + x0.w;
        o1.x = acc[i][4] + bo + x1.x; o1.y = acc[i][5] + bo + x1.y;
        o1.z = acc[i][6] + bo + x1.z; o1.w = acc[i][7] + bo + x1.w;
        *(float4*)(out + base) = o0;
        *(float4*)(out + base + 4) = o1;
    }
}

extern "C" void kernel_launch(void* const* d_in, const int* in_sizes, int n_in,
                              void* d_out, int out_size, void* d_ws, size_t ws_size,
                              hipStream_t stream) {
    (void)in_sizes; (void)n_in; (void)out_size; (void)ws_size;
    const float* x      = (const float*)d_in[0];
    const float* gamma  = (const float*)d_in[1];
    const float* beta   = (const float*)d_in[2];
    const float* wq     = (const float*)d_in[3];
    const float* wk     = (const float*)d_in[4];
    const float* wv     = (const float*)d_in[5];
    const float* w_out  = (const float*)d_in[6];
    const float* b_out  = (const float*)d_in[7];
    float* out = (float*)d_out;
    float* ws  = (float*)d_ws;

    float* qm    = ws + WS_QM;
    float* part3 = ws + WS_PART3;
    float* gnp   = ws + WS_GNPART;
    float* scale = ws + WS_SCALE;
    float* shift = ws + WS_SHIFT;
    float* ctx   = ws + WS_CTX;
    float* ksum  = ws + WS_KSUM;
    float* Amat  = ws + WS_AMAT;

    hipLaunchKernelGGL(gn_stats, dim3(BB * NGRP * KB_GN), dim3(256), 0, stream, x, gnp);
    hipLaunchKernelGGL(gn_finalize, dim3(1), dim3(256), 0, stream, gnp, gamma, beta, scale, shift);
    hipLaunchKernelGGL(qkv_ctx, dim3(NT3, NHEAD, BB), dim3(256), 0, stream,
                       x, scale, shift, wq, wk, wv, qm, part3);
    hipLaunchKernelGGL(ctx_reduce, dim3(BB * NHEAD), dim3(1024), 0, stream, part3, ctx, ksum);
    hipLaunchKernelGGL(build_A, dim3(8, BB), dim3(256), 0, stream, w_out, ctx, Amat);
    hipLaunchKernelGGL(final_out, dim3(NT3, CC / MT6, BB), dim3(256), 0, stream,
                       qm, Amat, ksum, b_out, x, out);
}

// Round 2
// 400.842 us; speedup vs baseline: 1.8047x; 1.8047x over previous
//
#include <hip/hip_runtime.h>
#include <math.h>

#define BB 2
#define CC 256
#define NHEAD 8
#define HD 32
#define NGRP 8
#define NNTOK 32768
#define ATT_EPS 1e-6f
#define GN_EPS 1e-5f
#define KB_GN 64

// ---------------- types / helpers ----------------
typedef __attribute__((ext_vector_type(8))) short bfrag8;   // 8 bf16 (4 VGPRs)
typedef __attribute__((ext_vector_type(4))) float accf4;    // MFMA C/D

__device__ __forceinline__ float b2f(unsigned short u) {
    unsigned int x = ((unsigned int)u) << 16;
    return __uint_as_float(x);
}
__device__ __forceinline__ unsigned short f2b(float f) {
    unsigned int x = __float_as_uint(f);
    unsigned int r = x + 0x7fffu + ((x >> 16) & 1u);
    return (unsigned short)(r >> 16);
}
__device__ __forceinline__ void gl_lds16(const void* g, void* s) {
    __builtin_amdgcn_global_load_lds(
        (const __attribute__((address_space(1))) unsigned int*)g,
        (__attribute__((address_space(3))) unsigned int*)s, 16, 0, 0);
}

// ---- workspace layout (float offsets) ----
// qm_t  : bf16 [B][H][N][32]                = 16,777,216 us = 8,388,608 f
// xn_t  : bf16 [B][N][264] (cols 256..263 pad)= 17,301,504 us = 8,650,752 f
// Wst   : bf16 [H][96][264] (+slack)        = 202,752 us -> 101,632 f
// part  : f32  [B*H][256 tiles][1056]       = 4,325,376 f
#define WS_QMT   0ull
#define WS_XNT   (WS_QMT + 8388608ull)
#define WS_WST   (WS_XNT + 8650752ull)
#define WS_PART  (WS_WST + 101632ull)
#define WS_GNP   (WS_PART + 4325376ull)
#define WS_SCALE (WS_GNP + 2048ull)
#define WS_SHIFT (WS_SCALE + 512ull)
#define WS_CTX   (WS_SHIFT + 512ull)
#define WS_KSUM  (WS_CTX + 16384ull)
#define WS_AMAT  (WS_KSUM + 512ull)          // bf16 [B][256][256] = 65536 f
#define WS_DEN   (WS_AMAT + 65536ull)        // f32 [B][H][N] = 524288 f

// LDS layout for qkv_ctx (dynamic, 147456 B total)
#define LDS_W    0        // 96 rows x 528 B (staged 50 KB)
#define LDS_XN   51200    // 128 rows x 528 B = 67584
#define LDS_KMV  118784   // 64 rows x 272 B = 17408 (km rows 0..31, v rows 32..63)
#define LDS_QS   136192   // 128 rows x 80 B = 10240 (qm [n][d])
#define LDS_KSP  146432   // 32x8 f32 = 1024
#define LDS_QKV_TOTAL 147456

// ============ Kernel 1: GroupNorm partial sums ============
__global__ __launch_bounds__(256) void gn_stats(const float* __restrict__ x,
                                                float* __restrict__ part) {
    int grp = blockIdx.x / KB_GN;
    int blk = blockIdx.x % KB_GN;
    const float* base = x + (size_t)grp * (CC / NGRP) * NNTOK + (size_t)blk * 16384;
    int t = threadIdx.x;
    float s = 0.f, s2 = 0.f;
    for (int i = 0; i < 16; ++i) {
        const float4 v = *(const float4*)(base + i * 1024 + t * 4);
        s  += v.x + v.y + v.z + v.w;
        s2 += v.x * v.x + v.y * v.y + v.z * v.z + v.w * v.w;
    }
    for (int off = 32; off; off >>= 1) {
        s  += __shfl_down(s, off);
        s2 += __shfl_down(s2, off);
    }
    __shared__ float ls[4], ls2[4];
    int wave = t >> 6;
    if ((t & 63) == 0) { ls[wave] = s; ls2[wave] = s2; }
    __syncthreads();
    if (t == 0) {
        part[(grp * KB_GN + blk) * 2 + 0] = ls[0] + ls[1] + ls[2] + ls[3];
        part[(grp * KB_GN + blk) * 2 + 1] = ls2[0] + ls2[1] + ls2[2] + ls2[3];
    }
}

// ============ Kernel 2: finalize GN -> per (b,c) scale/shift ============
__global__ __launch_bounds__(256) void gn_finalize(const float* __restrict__ part,
                                                   const float* __restrict__ gamma,
                                                   const float* __restrict__ beta,
                                                   float* __restrict__ scale,
                                                   float* __restrict__ shift) {
    __shared__ float mean_s[16], rstd_s[16];
    int t = threadIdx.x;
    if (t < 16) {
        float s = 0.f, s2 = 0.f;
        for (int i = 0; i < KB_GN; ++i) {
            s  += part[(t * KB_GN + i) * 2 + 0];
            s2 += part[(t * KB_GN + i) * 2 + 1];
        }
        const float inv = 1.0f / (float)((CC / NGRP) * NNTOK);
        float m = s * inv;
        float var = s2 * inv - m * m;
        mean_s[t] = m;
        rstd_s[t] = rsqrtf(var + GN_EPS);
    }
    __syncthreads();
    for (int idx = t; idx < BB * CC; idx += 256) {
        int b = idx / CC, c = idx % CC;
        int grp = b * NGRP + c / (CC / NGRP);
        float sc = gamma[c] * rstd_s[grp];
        scale[idx] = sc;
        shift[idx] = beta[c] - mean_s[grp] * sc;
    }
}

// ============ Kernel 3: stacked padded bf16 weights Wst[h][96][264] ============
__global__ __launch_bounds__(256) void prep_w(const float* __restrict__ wq,
                                              const float* __restrict__ wk,
                                              const float* __restrict__ wv,
                                              unsigned short* __restrict__ Wst) {
    int h = blockIdx.x, t = threadIdx.x;
    const float* Ws[3] = {wq, wk, wv};
    for (int i = t; i < 96 * 264; i += 256) {
        int r = i / 264, c = i % 264;
        float v = 0.f;
        if (c < 256) v = Ws[r >> 5][(size_t)(h * 32 + (r & 31)) * CC + c];
        Wst[(size_t)h * (96 * 264) + i] = f2b(v);
    }
}

// ============ Kernel 4: xn_t[b][n][264] bf16 (normalized, transposed, padded) ====
__global__ __launch_bounds__(256) void xn_prep(const float* __restrict__ x,
                                               const float* __restrict__ scale,
                                               const float* __restrict__ shift,
                                               unsigned short* __restrict__ xn_t) {
    __shared__ unsigned short xt[64][264];
    int b = blockIdx.y, n0 = blockIdx.x * 64, t = threadIdx.x;
    int col4 = (t & 15) * 4;
    for (int i = 0; i < 16; ++i) {
        int c = (t >> 4) + i * 16;
        float sc = scale[b * CC + c], sh = shift[b * CC + c];
        const float4 v = *(const float4*)(x + (size_t)(b * CC + c) * NNTOK + n0 + col4);
        xt[col4 + 0][c] = f2b(v.x * sc + sh);
        xt[col4 + 1][c] = f2b(v.y * sc + sh);
        xt[col4 + 2][c] = f2b(v.z * sc + sh);
        xt[col4 + 3][c] = f2b(v.w * sc + sh);
    }
    __syncthreads();
    // store rows (only valid 512B of each 528B row)
    int n = t >> 2, q = t & 3;
    const char* src = (const char*)&xt[n][0] + q * 128;
    char* dst = (char*)(xn_t + ((size_t)b * NNTOK + n0 + n) * 264) + q * 128;
    #pragma unroll
    for (int i = 0; i < 8; ++i)
        *(float4*)(dst + i * 16) = *(const float4*)(src + i * 16);
}

// ============ Kernel 5: fused QKV MFMA GEMM + elu + context/ksum partials ========
__global__ __launch_bounds__(256) void qkv_ctx(
    const unsigned short* __restrict__ xn_t, const unsigned short* __restrict__ Wst,
    unsigned short* __restrict__ qm_t, float* __restrict__ part) {
    extern __shared__ char lds[];
    const int tile = blockIdx.x, h = blockIdx.y, b = blockIdx.z;
    const int t = threadIdx.x;
    const int lane = t & 63, w = t >> 6;
    const int lr = lane & 15, lq = lane >> 4;
    const int n0 = tile * 128;

    // ---- stage W (50 KB) + xn tile (66 KB) via global_load_lds ----
    {
        const char* wg = (const char*)(Wst + (size_t)h * (96 * 264));
        char* wl = lds + LDS_W;
        for (int j = w; j < 50; j += 4)
            gl_lds16(wg + j * 1024 + lane * 16, wl + j * 1024);
        const char* xg = (const char*)(xn_t + ((size_t)b * NNTOK + n0) * 264);
        char* xl = lds + LDS_XN;
        for (int j = w; j < 66; j += 4)
            gl_lds16(xg + j * 1024 + lane * 16, xl + j * 1024);
    }
    __syncthreads();

    // ---- MFMA GEMM: D[96 m][128 n], wave w owns tokens [w*32, w*32+32) ----
    accf4 acc[6][2];
    #pragma unroll
    for (int i = 0; i < 6; ++i)
        #pragma unroll
        for (int j = 0; j < 2; ++j) acc[i][j] = (accf4){0.f, 0.f, 0.f, 0.f};

    const char* wl = lds + LDS_W;
    const char* xl = lds + LDS_XN;
    #pragma unroll
    for (int kc = 0; kc < 8; ++kc) {
        bfrag8 bfr[2];
        #pragma unroll
        for (int ci = 0; ci < 2; ++ci) {
            int n = w * 32 + ci * 16 + lr;
            bfr[ci] = *(const bfrag8*)(xl + n * 528 + kc * 64 + lq * 16);
        }
        #pragma unroll
        for (int mi = 0; mi < 6; ++mi) {
            bfrag8 a = *(const bfrag8*)(wl + (mi * 16 + lr) * 528 + kc * 64 + lq * 16);
            #pragma unroll
            for (int ci = 0; ci < 2; ++ci)
                acc[mi][ci] = __builtin_amdgcn_mfma_f32_16x16x32_bf16(a, bfr[ci], acc[mi][ci], 0, 0, 0);
        }
    }

    // ---- q -> elu+1 -> qs[n][d]; k -> elu+1 -> kmv[0..31][n]; v -> kmv[32..63][n] ----
    char* qs  = lds + LDS_QS;
    char* kmv = lds + LDS_KMV;
    #pragma unroll
    for (int mi = 0; mi < 2; ++mi)
        #pragma unroll
        for (int ci = 0; ci < 2; ++ci)
            #pragma unroll
            for (int r = 0; r < 4; ++r) {
                int d = mi * 16 + lq * 4 + r;
                int n = w * 32 + ci * 16 + lr;
                float q = acc[mi][ci][r];
                *(unsigned short*)(qs + n * 80 + d * 2) = f2b(q > 0.f ? q + 1.f : __expf(q));
            }
    #pragma unroll
    for (int mi = 2; mi < 4; ++mi)
        #pragma unroll
        for (int ci = 0; ci < 2; ++ci)
            #pragma unroll
            for (int r = 0; r < 4; ++r) {
                int d = (mi - 2) * 16 + lq * 4 + r;
                int n = w * 32 + ci * 16 + lr;
                float kk = acc[mi][ci][r];
                *(unsigned short*)(kmv + d * 272 + n * 2) = f2b(kk > 0.f ? kk + 1.f : __expf(kk));
            }
    #pragma unroll
    for (int mi = 4; mi < 6; ++mi)
        #pragma unroll
        for (int ci = 0; ci < 2; ++ci)
            #pragma unroll
            for (int r = 0; r < 4; ++r) {
                int e = (mi - 4) * 16 + lq * 4 + r;
                int n = w * 32 + ci * 16 + lr;
                *(unsigned short*)(kmv + (32 + e) * 272 + n * 2) = f2b(acc[mi][ci][r]);
            }
    __syncthreads();

    const size_t pb = (size_t)((b * NHEAD + h) * 256 + tile) * 1056;

    // ---- qm -> global (coalesced rows of 64 B) ----
    {
        char* qg = (char*)(qm_t + ((size_t)(b * NHEAD + h) * NNTOK + n0) * 32);
        int n = t >> 1, half = t & 1;
        const char* src = qs + n * 80 + half * 32;
        char* dst = qg + n * 64 + half * 32;
        *(float4*)dst = *(const float4*)src;
        *(float4*)(dst + 16) = *(const float4*)(src + 16);
    }

    // ---- context partial: wave w computes 16x16 quadrant (w>>1, w&1), K=128 ----
    {
        int qr = w >> 1, qc = w & 1;
        accf4 cacc = (accf4){0.f, 0.f, 0.f, 0.f};
        #pragma unroll
        for (int kk = 0; kk < 4; ++kk) {
            bfrag8 a  = *(const bfrag8*)(kmv + (qr * 16 + lr) * 272 + kk * 64 + lq * 16);
            bfrag8 bb = *(const bfrag8*)(kmv + (32 + qc * 16 + lr) * 272 + kk * 64 + lq * 16);
            cacc = __builtin_amdgcn_mfma_f32_16x16x32_bf16(a, bb, cacc, 0, 0, 0);
        }
        #pragma unroll
        for (int r = 0; r < 4; ++r) {
            int d = qr * 16 + lq * 4 + r, e = qc * 16 + lr;
            part[pb + d * 32 + e] = cacc[r];
        }
    }

    // ---- ksum partial over this tile's 128 tokens ----
    {
        float* ksp = (float*)(lds + LDS_KSP);
        int d = t >> 3, oc = t & 7;
        float s = 0.f;
        for (int i = 0; i < 16; ++i)
            s += b2f(*(const unsigned short*)(kmv + d * 272 + (oc * 16 + i) * 2));
        ksp[d * 8 + oc] = s;
        __syncthreads();
        if (t < 32) {
            float s2 = 0.f;
            #pragma unroll
            for (int i = 0; i < 8; ++i) s2 += ksp[t * 8 + i];
            part[pb + 1024 + t] = s2;
        }
    }
}

// ============ Kernel 6: reduce context/ksum partials ============
__global__ __launch_bounds__(1024) void ctx_reduce(const float* __restrict__ part,
                                                   float* __restrict__ ctx,
                                                   float* __restrict__ ksum) {
    int bh = blockIdx.x;
    int t = threadIdx.x;
    const float* p = part + (size_t)bh * 256 * 1056;
    float acc = 0.f, ks = 0.f;
    for (int tile = 0; tile < 256; ++tile) {
        acc += p[(size_t)tile * 1056 + t];
        if (t < 32) ks += p[(size_t)tile * 1056 + 1024 + t];
    }
    ctx[(size_t)bh * 1024 + t] = acc;
    if (t < 32) ksum[bh * 32 + t] = ks;
}

// ============ Kernel 7: A[b][o][h*32+d] = sum_e w_out[o][h*32+e]*ctx[b][h][d][e], bf16 ==
__global__ __launch_bounds__(256) void build_A(const float* __restrict__ w_out,
                                               const float* __restrict__ ctx,
                                               unsigned short* __restrict__ A) {
    int ot = blockIdx.x, b = blockIdx.y, t = threadIdx.x;
    __shared__ float cs[NHEAD][HD][HD];
    for (int i = t; i < NHEAD * HD * HD; i += 256)
        ((float*)cs)[i] = ctx[(size_t)b * NHEAD * HD * HD + i];
    __syncthreads();
    int h = t >> 5, d = t & 31;
    for (int oi = 0; oi < 32; ++oi) {
        int o = ot * 32 + oi;
        const float* wrow = w_out + (size_t)o * CC + h * HD;
        float s = 0.f;
        #pragma unroll
        for (int e = 0; e < HD; ++e) s += wrow[e] * cs[h][d][e];
        A[((size_t)b * CC + o) * CC + t] = f2b(s);
    }
}

// ============ Kernel 8: den[b][h][n] = 1/(qm . ksum + eps) ============
__global__ __launch_bounds__(256) void den_kernel(const unsigned short* __restrict__ qm_t,
                                                  const float* __restrict__ ksum,
                                                  float* __restrict__ den) {
    int nt = blockIdx.x, h = blockIdx.y, b = blockIdx.z, t = threadIdx.x;
    __shared__ float ks[32];
    if (t < 32) ks[t] = ksum[(b * NHEAD + h) * 32 + t];
    __syncthreads();
    int n = nt * 256 + t;
    const uint4* rp = (const uint4*)(qm_t + ((size_t)(b * NHEAD + h) * NNTOK + n) * 32);
    float s = 0.f;
    #pragma unroll
    for (int i = 0; i < 4; ++i) {
        uint4 u = rp[i];
        s += b2f(u.x & 0xffff) * ks[i * 8 + 0] + b2f(u.x >> 16) * ks[i * 8 + 1];
        s += b2f(u.y & 0xffff) * ks[i * 8 + 2] + b2f(u.y >> 16) * ks[i * 8 + 3];
        s += b2f(u.z & 0xffff) * ks[i * 8 + 4] + b2f(u.z >> 16) * ks[i * 8 + 5];
        s += b2f(u.w & 0xffff) * ks[i * 8 + 6] + b2f(u.w >> 16) * ks[i * 8 + 7];
    }
    den[(size_t)(b * NHEAD + h) * NNTOK + n] = 1.0f / (s + ATT_EPS);
}

// ============ Kernel 9: out = A @ (qm * den) + b_out + x  (MFMA) ============
#define LDSF_A   0
#define LDSF_Q   10240
#define LDSF_DEN 20480
#define LDSF_BO  20992
__global__ __launch_bounds__(256) void final_out(
    const unsigned short* __restrict__ qm_t, const unsigned short* __restrict__ Amat,
    const float* __restrict__ den, const float* __restrict__ b_out,
    const float* __restrict__ x, float* __restrict__ out) {
    __shared__ char L[21504];
    int tile = blockIdx.x, mt = blockIdx.y, b = blockIdx.z;
    int n0 = tile * 128, t = threadIdx.x;
    int lane = t & 63, w = t >> 6, lr = lane & 15, lq = lane >> 4;
    int wm = (w >> 1) * 64, wn = (w & 1) * 64;
    accf4 acc[4][4];
    #pragma unroll
    for (int i = 0; i < 4; ++i)
        #pragma unroll
        for (int j = 0; j < 4; ++j) acc[i][j] = (accf4){0.f, 0.f, 0.f, 0.f};

    if (t < 128) ((float*)(L + LDSF_BO))[t] = b_out[mt * 128 + t];

    char* Al = L + LDSF_A;
    char* Ql = L + LDSF_Q;
    for (int h = 0; h < NHEAD; ++h) {
        int m = t >> 1, half = t & 1;
        const char* ag = (const char*)(Amat + ((size_t)(b * CC + mt * 128 + m) * CC + h * 32)) + half * 32;
        float4 av0 = *(const float4*)ag, av1 = *(const float4*)(ag + 16);
        const char* qg = (const char*)(qm_t + ((size_t)(b * NHEAD + h) * NNTOK + n0 + m) * 32) + half * 32;
        float4 qv0 = *(const float4*)qg, qv1 = *(const float4*)(qg + 16);
        float dv = 0.f;
        if (t < 128) dv = den[(size_t)(b * NHEAD + h) * NNTOK + n0 + t];
        __syncthreads();   // previous iteration's MFMA reads done
        *(float4*)(Al + m * 80 + half * 32) = av0;
        *(float4*)(Al + m * 80 + half * 32 + 16) = av1;
        *(float4*)(Ql + m * 80 + half * 32) = qv0;
        *(float4*)(Ql + m * 80 + half * 32 + 16) = qv1;
        if (t < 128) ((float*)(L + LDSF_DEN))[t] = dv;
        __syncthreads();
        // rescale qm chunk by den (row-uniform scale)
        {
            int n = t >> 1, u = t & 1;
            float dn = ((float*)(L + LDSF_DEN))[n];
            char* p = Ql + n * 80 + u * 32;
            bfrag8 v0 = *(bfrag8*)p, v1 = *(bfrag8*)(p + 16);
            #pragma unroll
            for (int e = 0; e < 8; ++e) {
                v0[e] = (short)f2b(b2f((unsigned short)v0[e]) * dn);
                v1[e] = (short)f2b(b2f((unsigned short)v1[e]) * dn);
            }
            *(bfrag8*)p = v0;
            *(bfrag8*)(p + 16) = v1;
        }
        __syncthreads();
        // MFMA 64x64 per wave
        bfrag8 bfr[4];
        #pragma unroll
        for (int ci = 0; ci < 4; ++ci) {
            int n = wn + ci * 16 + lr;
            bfr[ci] = *(const bfrag8*)(Ql + n * 80 + lq * 16);
        }
        #pragma unroll
        for (int mi = 0; mi < 4; ++mi) {
            bfrag8 a = *(const bfrag8*)(Al + (wm + mi * 16 + lr) * 80 + lq * 16);
            #pragma unroll
            for (int ci = 0; ci < 4; ++ci)
                acc[mi][ci] = __builtin_amdgcn_mfma_f32_16x16x32_bf16(a, bfr[ci], acc[mi][ci], 0, 0, 0);
        }
        __syncthreads();   // protect LDS before next iteration's writes
    }

    const float* bo_s = (const float*)(L + LDSF_BO);
    #pragma unroll
    for (int mi = 0; mi < 4; ++mi)
        #pragma unroll
        for (int ci = 0; ci < 4; ++ci)
            #pragma unroll
            for (int r = 0; r < 4; ++r) {
                int ol = wm + mi * 16 + lq * 4 + r;
                int n = wn + ci * 16 + lr;
                size_t idx = ((size_t)(b * CC + mt * 128 + ol)) * NNTOK + n0 + n;
                out[idx] = acc[mi][ci][r] + bo_s[ol] + x[idx];
            }
}

extern "C" void kernel_launch(void* const* d_in, const int* in_sizes, int n_in,
                              void* d_out, int out_size, void* d_ws, size_t ws_size,
                              hipStream_t stream) {
    (void)in_sizes; (void)n_in; (void)out_size; (void)ws_size;
    const float* x      = (const float*)d_in[0];
    const float* gamma  = (const float*)d_in[1];
    const float* beta   = (const float*)d_in[2];
    const float* wq     = (const float*)d_in[3];
    const float* wk     = (const float*)d_in[4];
    const float* wv     = (const float*)d_in[5];
    const float* w_out  = (const float*)d_in[6];
    const float* b_out  = (const float*)d_in[7];
    float* out = (float*)d_out;
    float* ws  = (float*)d_ws;

    unsigned short* qm_t = (unsigned short*)(ws + WS_QMT);
    unsigned short* xn_t = (unsigned short*)(ws + WS_XNT);
    unsigned short* Wst  = (unsigned short*)(ws + WS_WST);
    float* part  = ws + WS_PART;
    float* gnp   = ws + WS_GNP;
    float* scale = ws + WS_SCALE;
    float* shift = ws + WS_SHIFT;
    float* ctx   = ws + WS_CTX;
    float* ksum  = ws + WS_KSUM;
    unsigned short* Amat = (unsigned short*)(ws + WS_AMAT);
    float* den   = ws + WS_DEN;

    hipFuncSetAttribute((const void*)qkv_ctx,
                        hipFuncAttributeMaxDynamicSharedMemorySize, LDS_QKV_TOTAL);

    hipLaunchKernelGGL(gn_stats, dim3(BB * NGRP * KB_GN), dim3(256), 0, stream, x, gnp);
    hipLaunchKernelGGL(gn_finalize, dim3(1), dim3(256), 0, stream, gnp, gamma, beta, scale, shift);
    hipLaunchKernelGGL(prep_w, dim3(NHEAD), dim3(256), 0, stream, wq, wk, wv, Wst);
    hipLaunchKernelGGL(xn_prep, dim3(NNTOK / 64, BB), dim3(256), 0, stream, x, scale, shift, xn_t);
    hipLaunchKernelGGL(qkv_ctx, dim3(NNTOK / 128, NHEAD, BB), dim3(256), LDS_QKV_TOTAL, stream,
                       xn_t, Wst, qm_t, part);
    hipLaunchKernelGGL(ctx_reduce, dim3(BB * NHEAD), dim3(1024), 0, stream, part, ctx, ksum);
    hipLaunchKernelGGL(build_A, dim3(8, BB), dim3(256), 0, stream, w_out, ctx, Amat);
    hipLaunchKernelGGL(den_kernel, dim3(NNTOK / 256, NHEAD, BB), dim3(256), 0, stream,
                       qm_t, ksum, den);
    hipLaunchKernelGGL(final_out, dim3(NNTOK / 128, 2, BB), dim3(256), 0, stream,
                       qm_t, Amat, den, b_out, x, out);
}

// Round 4
// 352.694 us; speedup vs baseline: 2.0511x; 1.1365x over previous
//
#include <hip/hip_runtime.h>
#include <math.h>

#define BB 2
#define CC 256
#define NHEAD 8
#define HD 32
#define NGRP 8
#define NNTOK 32768
#define ATT_EPS 1e-6f
#define GN_EPS 1e-5f
#define KB_GN 64

typedef __attribute__((ext_vector_type(8))) short bfrag8;   // 8 bf16
typedef __attribute__((ext_vector_type(4))) float accf4;    // MFMA C/D 16x16

__device__ __forceinline__ float b2f(unsigned short u) {
    unsigned int x = ((unsigned int)u) << 16;
    return __uint_as_float(x);
}
__device__ __forceinline__ unsigned short f2b(float f) {
    unsigned int x = __float_as_uint(f);
    unsigned int r = x + 0x7fffu + ((x >> 16) & 1u);
    return (unsigned short)(r >> 16);
}
__device__ __forceinline__ void gl_lds16(const void* g, void* s) {
    __builtin_amdgcn_global_load_lds(
        (const __attribute__((address_space(1))) unsigned int*)g,
        (__attribute__((address_space(3))) unsigned int*)s, 16, 0, 0);
}

// ---- workspace layout (float offsets) — identical to the verified round-2 map ----
#define WS_QMT   0ull            // bf16 [B][H][N][32]
#define WS_XNT   (WS_QMT + 8388608ull)    // bf16 [B][N][264] padded
#define WS_WST   (WS_XNT + 8650752ull)    // bf16 [H][96][264] padded
#define WS_PART  (WS_WST + 101632ull)     // f32 [16 bh][256 tiles][1056]
#define WS_GNP   (WS_PART + 4325376ull)
#define WS_SCALE (WS_GNP + 2048ull)
#define WS_SHIFT (WS_SCALE + 512ull)
#define WS_CTX   (WS_SHIFT + 512ull)      // (unused, kept for layout stability)
#define WS_KSUM  (WS_CTX + 16384ull)      // f32 [B][H][32]
#define WS_AMAT  (WS_KSUM + 512ull)       // bf16 [B][256][256]
#define WS_DEN   (WS_AMAT + 65536ull)     // f32 [B][H][N]; part2 aliases this
#define WS_PART2 WS_DEN                   // f32 [16 bh][16][1056] = 270336 < 524288

// LDS for qkv_ctx (dynamic, 67584 B): xs 128x528 staged; after barrier overlay:
// kmv 64x272 @0, qs 128x80 @17408, ksp @27648
#define LDS_QS_OFF  17408
#define LDS_KSP_OFF 27648
#define LDS_QKV_TOTAL 67584

// ============ Kernel 1: GroupNorm partial sums (R2 verbatim) ============
__global__ __launch_bounds__(256) void gn_stats(const float* __restrict__ x,
                                                float* __restrict__ part) {
    int grp = blockIdx.x / KB_GN;
    int blk = blockIdx.x % KB_GN;
    const float* base = x + (size_t)grp * (CC / NGRP) * NNTOK + (size_t)blk * 16384;
    int t = threadIdx.x;
    float s = 0.f, s2 = 0.f;
    for (int i = 0; i < 16; ++i) {
        const float4 v = *(const float4*)(base + i * 1024 + t * 4);
        s  += v.x + v.y + v.z + v.w;
        s2 += v.x * v.x + v.y * v.y + v.z * v.z + v.w * v.w;
    }
    for (int off = 32; off; off >>= 1) {
        s  += __shfl_down(s, off);
        s2 += __shfl_down(s2, off);
    }
    __shared__ float ls[4], ls2[4];
    int wave = t >> 6;
    if ((t & 63) == 0) { ls[wave] = s; ls2[wave] = s2; }
    __syncthreads();
    if (t == 0) {
        part[(grp * KB_GN + blk) * 2 + 0] = ls[0] + ls[1] + ls[2] + ls[3];
        part[(grp * KB_GN + blk) * 2 + 1] = ls2[0] + ls2[1] + ls2[2] + ls2[3];
    }
}

// ============ Kernel 2: finalize GN (R2 verbatim) ============
__global__ __launch_bounds__(256) void gn_finalize(const float* __restrict__ part,
                                                   const float* __restrict__ gamma,
                                                   const float* __restrict__ beta,
                                                   float* __restrict__ scale,
                                                   float* __restrict__ shift) {
    __shared__ float mean_s[16], rstd_s[16];
    int t = threadIdx.x;
    if (t < 16) {
        float s = 0.f, s2 = 0.f;
        for (int i = 0; i < KB_GN; ++i) {
            s  += part[(t * KB_GN + i) * 2 + 0];
            s2 += part[(t * KB_GN + i) * 2 + 1];
        }
        const float inv = 1.0f / (float)((CC / NGRP) * NNTOK);
        float m = s * inv;
        float var = s2 * inv - m * m;
        mean_s[t] = m;
        rstd_s[t] = rsqrtf(var + GN_EPS);
    }
    __syncthreads();
    for (int idx = t; idx < BB * CC; idx += 256) {
        int b = idx / CC, c = idx % CC;
        int grp = b * NGRP + c / (CC / NGRP);
        float sc = gamma[c] * rstd_s[grp];
        scale[idx] = sc;
        shift[idx] = beta[c] - mean_s[grp] * sc;
    }
}

// ============ Kernel 3: Wst[h][96][264] bf16 padded (R2 verbatim) ============
__global__ __launch_bounds__(256) void prep_w(const float* __restrict__ wq,
                                              const float* __restrict__ wk,
                                              const float* __restrict__ wv,
                                              unsigned short* __restrict__ Wst) {
    int h = blockIdx.x, t = threadIdx.x;
    const float* Ws[3] = {wq, wk, wv};
    for (int i = t; i < 96 * 264; i += 256) {
        int r = i / 264, c = i % 264;
        float v = 0.f;
        if (c < 256) v = Ws[r >> 5][(size_t)(h * 32 + (r & 31)) * CC + c];
        Wst[(size_t)h * (96 * 264) + i] = f2b(v);
    }
}

// ============ Kernel 4: xn_t[b][n][264] bf16 (R2 verbatim) ============
__global__ __launch_bounds__(256) void xn_prep(const float* __restrict__ x,
                                               const float* __restrict__ scale,
                                               const float* __restrict__ shift,
                                               unsigned short* __restrict__ xn_t) {
    __shared__ unsigned short xt[64][264];
    int b = blockIdx.y, n0 = blockIdx.x * 64, t = threadIdx.x;
    int col4 = (t & 15) * 4;
    for (int i = 0; i < 16; ++i) {
        int c = (t >> 4) + i * 16;
        float sc = scale[b * CC + c], sh = shift[b * CC + c];
        const float4 v = *(const float4*)(x + (size_t)(b * CC + c) * NNTOK + n0 + col4);
        xt[col4 + 0][c] = f2b(v.x * sc + sh);
        xt[col4 + 1][c] = f2b(v.y * sc + sh);
        xt[col4 + 2][c] = f2b(v.z * sc + sh);
        xt[col4 + 3][c] = f2b(v.w * sc + sh);
    }
    __syncthreads();
    int n = t >> 2, q = t & 3;
    const char* src = (const char*)&xt[n][0] + q * 128;
    char* dst = (char*)(xn_t + ((size_t)b * NNTOK + n0 + n) * 264) + q * 128;
    #pragma unroll
    for (int i = 0; i < 8; ++i)
        *(float4*)(dst + i * 16) = *(const float4*)(src + i * 16);
}

// ============ Kernel 5: fused QKV MFMA + elu + ctx/ksum partials ============
// R2-verified structure; changes: W A-frags from global (per-kc prefetch, same
// addressing as the verified LDS reads), epilogue buffers overlaid into the xs
// region behind an extra barrier. LDS 147->67.6 KB => 2 blocks/CU.
__global__ __launch_bounds__(256, 2) void qkv_ctx(
    const unsigned short* __restrict__ xn_t, const unsigned short* __restrict__ Wst,
    unsigned short* __restrict__ qm_t, float* __restrict__ part) {
    extern __shared__ char lds[];
    const int tile = blockIdx.x, h = blockIdx.y, b = blockIdx.z;
    const int t = threadIdx.x;
    const int lane = t & 63, w = t >> 6;
    const int lr = lane & 15, lq = lane >> 4;
    const int n0 = tile * 128;

    // stage xn tile (128 x 528 B) via global_load_lds, R2 verbatim
    {
        const char* xg = (const char*)(xn_t + ((size_t)b * NNTOK + n0) * 264);
        for (int j = w; j < 66; j += 4)
            gl_lds16(xg + j * 1024 + lane * 16, lds + j * 1024);
    }
    __syncthreads();

    accf4 acc[6][2];
    #pragma unroll
    for (int i = 0; i < 6; ++i)
        #pragma unroll
        for (int j = 0; j < 2; ++j) acc[i][j] = (accf4){0.f, 0.f, 0.f, 0.f};

    const unsigned short* Wg = Wst + (size_t)h * (96 * 264);
    const char* xl = lds;
    // prefetch W frags for kc=0 (elements kc*32 + lq*8, row mi*16+lr — identical
    // math to R2's verified LDS read (mi*16+lr)*528B + kc*64B + lq*16B)
    bfrag8 wnx[6];
    #pragma unroll
    for (int mi = 0; mi < 6; ++mi)
        wnx[mi] = *(const bfrag8*)(Wg + (mi * 16 + lr) * 264 + lq * 8);

    #pragma unroll
    for (int kc = 0; kc < 8; ++kc) {
        bfrag8 wcur[6];
        #pragma unroll
        for (int mi = 0; mi < 6; ++mi) wcur[mi] = wnx[mi];
        if (kc < 7) {
            #pragma unroll
            for (int mi = 0; mi < 6; ++mi)
                wnx[mi] = *(const bfrag8*)(Wg + (mi * 16 + lr) * 264 + (kc + 1) * 32 + lq * 8);
        }
        bfrag8 bfr[2];
        #pragma unroll
        for (int ci = 0; ci < 2; ++ci) {
            int n = w * 32 + ci * 16 + lr;
            bfr[ci] = *(const bfrag8*)(xl + n * 528 + kc * 64 + lq * 16);
        }
        #pragma unroll
        for (int mi = 0; mi < 6; ++mi)
            #pragma unroll
            for (int ci = 0; ci < 2; ++ci)
                acc[mi][ci] = __builtin_amdgcn_mfma_f32_16x16x32_bf16(wcur[mi], bfr[ci], acc[mi][ci], 0, 0, 0);
    }
    __syncthreads();   // all waves done reading xs — overlay region now safe

    // epilogue (R2 verbatim, overlay pointers)
    char* kmv = lds;                 // km rows 0..31, v rows 32..63, stride 272
    char* qs  = lds + LDS_QS_OFF;    // qm [n 128][80 B]
    #pragma unroll
    for (int mi = 0; mi < 2; ++mi)
        #pragma unroll
        for (int ci = 0; ci < 2; ++ci)
            #pragma unroll
            for (int r = 0; r < 4; ++r) {
                int d = mi * 16 + lq * 4 + r;
                int n = w * 32 + ci * 16 + lr;
                float q = acc[mi][ci][r];
                *(unsigned short*)(qs + n * 80 + d * 2) = f2b(q > 0.f ? q + 1.f : expf(q));
            }
    #pragma unroll
    for (int mi = 2; mi < 4; ++mi)
        #pragma unroll
        for (int ci = 0; ci < 2; ++ci)
            #pragma unroll
            for (int r = 0; r < 4; ++r) {
                int d = (mi - 2) * 16 + lq * 4 + r;
                int n = w * 32 + ci * 16 + lr;
                float kk = acc[mi][ci][r];
                *(unsigned short*)(kmv + d * 272 + n * 2) = f2b(kk > 0.f ? kk + 1.f : expf(kk));
            }
    #pragma unroll
    for (int mi = 4; mi < 6; ++mi)
        #pragma unroll
        for (int ci = 0; ci < 2; ++ci)
            #pragma unroll
            for (int r = 0; r < 4; ++r) {
                int e = (mi - 4) * 16 + lq * 4 + r;
                int n = w * 32 + ci * 16 + lr;
                *(unsigned short*)(kmv + (32 + e) * 272 + n * 2) = f2b(acc[mi][ci][r]);
            }
    __syncthreads();

    const size_t pb = (size_t)((b * NHEAD + h) * 256 + tile) * 1056;

    // qm -> global (R2 verbatim)
    {
        char* qg = (char*)(qm_t + ((size_t)(b * NHEAD + h) * NNTOK + n0) * 32);
        int n = t >> 1, half = t & 1;
        const char* src = qs + n * 80 + half * 32;
        char* dst = qg + n * 64 + half * 32;
        *(float4*)dst = *(const float4*)src;
        *(float4*)(dst + 16) = *(const float4*)(src + 16);
    }

    // context quadrant per wave, K=128 (R2 verbatim)
    {
        int qr = w >> 1, qc = w & 1;
        accf4 cacc = (accf4){0.f, 0.f, 0.f, 0.f};
        #pragma unroll
        for (int kk = 0; kk < 4; ++kk) {
            bfrag8 a  = *(const bfrag8*)(kmv + (qr * 16 + lr) * 272 + kk * 64 + lq * 16);
            bfrag8 bb = *(const bfrag8*)(kmv + (32 + qc * 16 + lr) * 272 + kk * 64 + lq * 16);
            cacc = __builtin_amdgcn_mfma_f32_16x16x32_bf16(a, bb, cacc, 0, 0, 0);
        }
        #pragma unroll
        for (int r = 0; r < 4; ++r) {
            int d = qr * 16 + lq * 4 + r, e = qc * 16 + lr;
            part[pb + d * 32 + e] = cacc[r];
        }
    }

    // ksum partial (R2 verbatim)
    {
        float* ksp = (float*)(lds + LDS_KSP_OFF);
        int d = t >> 3, oc = t & 7;
        float s = 0.f;
        for (int i = 0; i < 16; ++i)
            s += b2f(*(const unsigned short*)(kmv + d * 272 + (oc * 16 + i) * 2));
        ksp[d * 8 + oc] = s;
        __syncthreads();
        if (t < 32) {
            float s2 = 0.f;
            #pragma unroll
            for (int i = 0; i < 8; ++i) s2 += ksp[t * 8 + i];
            part[pb + 1024 + t] = s2;
        }
    }
}

// ============ Kernel 6: reduce 256 tile-records -> 16 per bh ============
__global__ __launch_bounds__(256) void reduce1(const float* __restrict__ part,
                                               float* __restrict__ part2) {
    int chunk = blockIdx.x, bh = blockIdx.y, t = threadIdx.x;
    const float* p = part + ((size_t)bh * 256 + chunk * 16) * 1056;
    for (int i = t; i < 1056; i += 256) {
        float s = 0.f;
        #pragma unroll
        for (int j = 0; j < 16; ++j) s += p[(size_t)j * 1056 + i];
        part2[((size_t)bh * 16 + chunk) * 1056 + i] = s;
    }
}

// ============ Kernel 7: build A (bf16) + finalize ksum ============
__global__ __launch_bounds__(256) void build_A(const float* __restrict__ w_out,
                                               const float* __restrict__ part2,
                                               unsigned short* __restrict__ Amat,
                                               float* __restrict__ ksum_g) {
    int ot = blockIdx.x, b = blockIdx.y, t = threadIdx.x;
    __shared__ float cs[NHEAD * HD * HD];
    for (int i = t; i < NHEAD * HD * HD; i += 256) {
        int hh = i >> 10, de = i & 1023;
        const float* p2 = part2 + (size_t)(b * NHEAD + hh) * 16 * 1056;
        float s = 0.f;
        #pragma unroll
        for (int c16 = 0; c16 < 16; ++c16) s += p2[(size_t)c16 * 1056 + de];
        cs[i] = s;
    }
    if (ot == 0) {
        const float* p2 = part2 + (size_t)(b * NHEAD + (t >> 5)) * 16 * 1056;
        float s = 0.f;
        #pragma unroll
        for (int c16 = 0; c16 < 16; ++c16) s += p2[(size_t)c16 * 1056 + 1024 + (t & 31)];
        ksum_g[b * CC + t] = s;
    }
    __syncthreads();
    int h = t >> 5, d = t & 31;
    for (int oi = 0; oi < 32; ++oi) {
        int o = ot * 32 + oi;
        const float* wrow = w_out + (size_t)o * CC + h * HD;
        float s = 0.f;
        #pragma unroll
        for (int e = 0; e < HD; ++e) s += wrow[e] * cs[h * 1024 + d * 32 + e];
        Amat[((size_t)(b * CC + o)) * CC + t] = f2b(s);
    }
}

// ============ Kernel 8: den (R2 verbatim) ============
__global__ __launch_bounds__(256) void den_kernel(const unsigned short* __restrict__ qm_t,
                                                  const float* __restrict__ ksum,
                                                  float* __restrict__ den) {
    int nt = blockIdx.x, h = blockIdx.y, b = blockIdx.z, t = threadIdx.x;
    __shared__ float ks[32];
    if (t < 32) ks[t] = ksum[(b * NHEAD + h) * 32 + t];
    __syncthreads();
    int n = nt * 256 + t;
    const uint4* rp = (const uint4*)(qm_t + ((size_t)(b * NHEAD + h) * NNTOK + n) * 32);
    float s = 0.f;
    #pragma unroll
    for (int i = 0; i < 4; ++i) {
        uint4 u = rp[i];
        s += b2f(u.x & 0xffff) * ks[i * 8 + 0] + b2f(u.x >> 16) * ks[i * 8 + 1];
        s += b2f(u.y & 0xffff) * ks[i * 8 + 2] + b2f(u.y >> 16) * ks[i * 8 + 3];
        s += b2f(u.z & 0xffff) * ks[i * 8 + 4] + b2f(u.z >> 16) * ks[i * 8 + 5];
        s += b2f(u.w & 0xffff) * ks[i * 8 + 6] + b2f(u.w >> 16) * ks[i * 8 + 7];
    }
    den[(size_t)(b * NHEAD + h) * NNTOK + n] = 1.0f / (s + ATT_EPS);
}

// ============ Kernel 9: out = A @ (qm*den) + b_out + x (R2 verbatim) ============
#define LDSF_A   0
#define LDSF_Q   10240
#define LDSF_DEN 20480
#define LDSF_BO  20992
__global__ __launch_bounds__(256, 2) void final_out(
    const unsigned short* __restrict__ qm_t, const unsigned short* __restrict__ Amat,
    const float* __restrict__ den, const float* __restrict__ b_out,
    const float* __restrict__ x, float* __restrict__ out) {
    __shared__ char L[21504];
    int tile = blockIdx.x, mt = blockIdx.y, b = blockIdx.z;
    int n0 = tile * 128, t = threadIdx.x;
    int lane = t & 63, w = t >> 6, lr = lane & 15, lq = lane >> 4;
    int wm = (w >> 1) * 64, wn = (w & 1) * 64;
    accf4 acc[4][4];
    #pragma unroll
    for (int i = 0; i < 4; ++i)
        #pragma unroll
        for (int j = 0; j < 4; ++j) acc[i][j] = (accf4){0.f, 0.f, 0.f, 0.f};

    if (t < 128) ((float*)(L + LDSF_BO))[t] = b_out[mt * 128 + t];

    char* Al = L + LDSF_A;
    char* Ql = L + LDSF_Q;
    for (int h = 0; h < NHEAD; ++h) {
        int m = t >> 1, half = t & 1;
        const char* ag = (const char*)(Amat + ((size_t)(b * CC + mt * 128 + m) * CC + h * 32)) + half * 32;
        float4 av0 = *(const float4*)ag, av1 = *(const float4*)(ag + 16);
        const char* qg = (const char*)(qm_t + ((size_t)(b * NHEAD + h) * NNTOK + n0 + m) * 32) + half * 32;
        float4 qv0 = *(const float4*)qg, qv1 = *(const float4*)(qg + 16);
        float dv = 0.f;
        if (t < 128) dv = den[(size_t)(b * NHEAD + h) * NNTOK + n0 + t];
        __syncthreads();
        *(float4*)(Al + m * 80 + half * 32) = av0;
        *(float4*)(Al + m * 80 + half * 32 + 16) = av1;
        *(float4*)(Ql + m * 80 + half * 32) = qv0;
        *(float4*)(Ql + m * 80 + half * 32 + 16) = qv1;
        if (t < 128) ((float*)(L + LDSF_DEN))[t] = dv;
        __syncthreads();
        {
            int n = t >> 1, u = t & 1;
            float dn = ((float*)(L + LDSF_DEN))[n];
            char* p = Ql + n * 80 + u * 32;
            bfrag8 v0 = *(bfrag8*)p, v1 = *(bfrag8*)(p + 16);
            #pragma unroll
            for (int e = 0; e < 8; ++e) {
                v0[e] = (short)f2b(b2f((unsigned short)v0[e]) * dn);
                v1[e] = (short)f2b(b2f((unsigned short)v1[e]) * dn);
            }
            *(bfrag8*)p = v0;
            *(bfrag8*)(p + 16) = v1;
        }
        __syncthreads();
        bfrag8 bfr[4];
        #pragma unroll
        for (int ci = 0; ci < 4; ++ci) {
            int n = wn + ci * 16 + lr;
            bfr[ci] = *(const bfrag8*)(Ql + n * 80 + lq * 16);
        }
        #pragma unroll
        for (int mi = 0; mi < 4; ++mi) {
            bfrag8 a = *(const bfrag8*)(Al + (wm + mi * 16 + lr) * 80 + lq * 16);
            #pragma unroll
            for (int ci = 0; ci < 4; ++ci)
                acc[mi][ci] = __builtin_amdgcn_mfma_f32_16x16x32_bf16(a, bfr[ci], acc[mi][ci], 0, 0, 0);
        }
        __syncthreads();
    }

    const float* bo_s = (const float*)(L + LDSF_BO);
    #pragma unroll
    for (int mi = 0; mi < 4; ++mi)
        #pragma unroll
        for (int ci = 0; ci < 4; ++ci)
            #pragma unroll
            for (int r = 0; r < 4; ++r) {
                int ol = wm + mi * 16 + lq * 4 + r;
                int n = wn + ci * 16 + lr;
                size_t idx = ((size_t)(b * CC + mt * 128 + ol)) * NNTOK + n0 + n;
                out[idx] = acc[mi][ci][r] + bo_s[ol] + x[idx];
            }
}

extern "C" void kernel_launch(void* const* d_in, const int* in_sizes, int n_in,
                              void* d_out, int out_size, void* d_ws, size_t ws_size,
                              hipStream_t stream) {
    (void)in_sizes; (void)n_in; (void)out_size; (void)ws_size;
    const float* x      = (const float*)d_in[0];
    const float* gamma  = (const float*)d_in[1];
    const float* beta   = (const float*)d_in[2];
    const float* wq     = (const float*)d_in[3];
    const float* wk     = (const float*)d_in[4];
    const float* wv     = (const float*)d_in[5];
    const float* w_out  = (const float*)d_in[6];
    const float* b_out  = (const float*)d_in[7];
    float* out = (float*)d_out;
    float* ws  = (float*)d_ws;

    unsigned short* qm_t = (unsigned short*)(ws + WS_QMT);
    unsigned short* xn_t = (unsigned short*)(ws + WS_XNT);
    unsigned short* Wst  = (unsigned short*)(ws + WS_WST);
    float* part  = ws + WS_PART;
    float* part2 = ws + WS_PART2;   // aliases den region (read before den writes)
    float* gnp   = ws + WS_GNP;
    float* scale = ws + WS_SCALE;
    float* shift = ws + WS_SHIFT;
    float* ksum  = ws + WS_KSUM;
    unsigned short* Amat = (unsigned short*)(ws + WS_AMAT);
    float* den   = ws + WS_DEN;

    hipFuncSetAttribute((const void*)qkv_ctx,
                        hipFuncAttributeMaxDynamicSharedMemorySize, LDS_QKV_TOTAL);

    hipLaunchKernelGGL(gn_stats, dim3(BB * NGRP * KB_GN), dim3(256), 0, stream, x, gnp);
    hipLaunchKernelGGL(gn_finalize, dim3(1), dim3(256), 0, stream, gnp, gamma, beta, scale, shift);
    hipLaunchKernelGGL(prep_w, dim3(NHEAD), dim3(256), 0, stream, wq, wk, wv, Wst);
    hipLaunchKernelGGL(xn_prep, dim3(NNTOK / 64, BB), dim3(256), 0, stream, x, scale, shift, xn_t);
    hipLaunchKernelGGL(qkv_ctx, dim3(NNTOK / 128, NHEAD, BB), dim3(256), LDS_QKV_TOTAL, stream,
                       xn_t, Wst, qm_t, part);
    hipLaunchKernelGGL(reduce1, dim3(16, 16), dim3(256), 0, stream, part, part2);
    hipLaunchKernelGGL(build_A, dim3(8, BB), dim3(256), 0, stream, w_out, part2, Amat, ksum);
    hipLaunchKernelGGL(den_kernel, dim3(NNTOK / 256, NHEAD, BB), dim3(256), 0, stream,
                       qm_t, ksum, den);
    hipLaunchKernelGGL(final_out, dim3(NNTOK / 128, 2, BB), dim3(256), 0, stream,
                       qm_t, Amat, den, b_out, x, out);
}